// Round 6
// baseline (604.047 us; speedup 1.0000x reference)
//
#include <hip/hip_runtime.h>
#include <hip/hip_bf16.h>

// MoLoRA = base linear + top-2 routed LoRA.
//   Abuf[T,2176] = [ bf16(x) | bf16(alpha*cw*(x@A2^T)) ]      (A2 = A_w as [128,2048])
//   Bfull[O,2176] = [ bf16(W) | bf16(B2^T) ]   (B2[e*16+r,o]=B_w[e,o,r])
//   out[T,O] = Abuf @ Bfull^T     -- single bf16 MFMA GEMM, K=2176
// T=4096, H=2048, O=2048, E=8, R=16, Kaug=2176.
//
// R1: XOR k-chunk LDS swizzle -> SQ_LDS_BANK_CONFLICT 1.34e7 -> 0.
// R2-R4: tile/occupancy: 128x128 tile, 512 thr (8 waves of 64x32), 512 blocks
//   = 16 waves/CU -> 44.9 us (813 TF, the HIP-source m97-structure plateau).
// R5 (this): mega-setup = conversions + router + t2 in ONE dispatch using
//   in-dispatch producer->consumer flags (t2 blocks dispatched last; in-order
//   dispatch guarantees progress). 2 dispatches total. Fixed ~100 us harness
//   floor (restore/poison) is out of reach; kernel time 69 -> ~62 us.

typedef __bf16 bf16x8 __attribute__((ext_vector_type(8)));
typedef float f32x4 __attribute__((ext_vector_type(4)));

#define FLAG_MAGIC 0x13579B

__device__ __forceinline__ __bf16 f2bf(float f) {
  union { float f; unsigned u; } v; v.f = f;
  unsigned r = (v.u + 0x7FFFu + ((v.u >> 16) & 1u)) >> 16;  // RNE
  unsigned short s = (unsigned short)r;
  return __builtin_bit_cast(__bf16, s);
}

__device__ __forceinline__ void ld_lds16(const void* g, void* l) {
  __builtin_amdgcn_global_load_lds((__attribute__((address_space(1))) void*)g,
                                   (__attribute__((address_space(3))) void*)l,
                                   16, 0, 0);
}

__device__ __forceinline__ void flag_release(int* f) {
  __threadfence();  // agent-scope release: L2 writeback of this block's stores
  __hip_atomic_store(f, FLAG_MAGIC, __ATOMIC_RELEASE, __HIP_MEMORY_SCOPE_AGENT);
}

__device__ __forceinline__ void flag_spin(const int* f) {
  while (__hip_atomic_load(f, __ATOMIC_ACQUIRE, __HIP_MEMORY_SCOPE_AGENT) !=
         FLAG_MAGIC)
    __builtin_amdgcn_s_sleep(8);
}

// ---------------- mega-setup: one dispatch, 6336 blocks -------------------
// b in [0,2048)    : W row b -> bf16 -> Bfull[b, 0:2048]
// b in [2048,2176) : Aw row (b-2048) -> bf16 -> A2; release a2flag[b-2048]
// b in [2176,2240) : Bw pack into Bfull[:, 2048:2176]
// b in [2240,4288) : router+xconv, 2 tokens: x->bf16->Abuf[:,0:2048], fp32
//                    logits + top-2 -> cw; release tokflag[b-2240]
// b in [4288,6336) : t2 (tile=idx>>3, expert=idx&7): spin on 8 tokflags +
//                    128 a2flags, then Abuf[:,2048:] = bf16(16*cw*(x@A2^T))
__global__ __launch_bounds__(256) void setup_kernel(
    const float* __restrict__ W, const float* __restrict__ Aw,
    const float* __restrict__ Bw, const float* __restrict__ x,
    const float* __restrict__ gw, __bf16* __restrict__ Bfull,
    __bf16* __restrict__ A2, __bf16* __restrict__ Abuf,
    float* __restrict__ cw, int* __restrict__ tokflag,
    int* __restrict__ a2flag) {
  __shared__ float red[256][17];
  __shared__ float red2[16][17];
  __shared__ f32x4 part[4][64];
  const int b = blockIdx.x, tid = threadIdx.x;

  if (b < 2176) {
    const float* src = (b < 2048) ? (W + (size_t)b * 2048)
                                  : (Aw + (size_t)(b - 2048) * 2048);
    __bf16* dst = (b < 2048) ? (Bfull + (size_t)b * 2176)
                             : (A2 + (size_t)(b - 2048) * 2048);
    const int c = tid * 8;
    float4 a = *(const float4*)(src + c);
    float4 d = *(const float4*)(src + c + 4);
    bf16x8 v;
    v[0] = f2bf(a.x); v[1] = f2bf(a.y); v[2] = f2bf(a.z); v[3] = f2bf(a.w);
    v[4] = f2bf(d.x); v[5] = f2bf(d.y); v[6] = f2bf(d.z); v[7] = f2bf(d.w);
    *(bf16x8*)(dst + c) = v;
    if (b >= 2048) {
      __syncthreads();  // waves drain vmcnt before barrier -> stores in L2
      if (tid == 0) flag_release(&a2flag[b - 2048]);
    }
    return;
  }
  if (b < 2240) {
    const int idx = (b - 2176) * 256 + tid;  // 0..16383
    const int e = idx >> 11, o = idx & 2047;
    const float4* s = (const float4*)(Bw + ((size_t)e * 2048 + o) * 16);
    float4 v0 = s[0], v1 = s[1], v2 = s[2], v3 = s[3];
    __bf16* d = Bfull + (size_t)o * 2176 + 2048 + e * 16;
    bf16x8 lo, hi;
    lo[0] = f2bf(v0.x); lo[1] = f2bf(v0.y); lo[2] = f2bf(v0.z); lo[3] = f2bf(v0.w);
    lo[4] = f2bf(v1.x); lo[5] = f2bf(v1.y); lo[6] = f2bf(v1.z); lo[7] = f2bf(v1.w);
    hi[0] = f2bf(v2.x); hi[1] = f2bf(v2.y); hi[2] = f2bf(v2.z); hi[3] = f2bf(v2.w);
    hi[4] = f2bf(v3.x); hi[5] = f2bf(v3.y); hi[6] = f2bf(v3.z); hi[7] = f2bf(v3.w);
    *(bf16x8*)d = lo;
    *(bf16x8*)(d + 8) = hi;
    return;
  }
  if (b < 4288) {
    // ---- router + x->bf16, 2 tokens ----
    const int t0 = (b - 2240) * 2;
    const int c = tid * 8;
    float4 a0 = *(const float4*)(x + (size_t)t0 * 2048 + c);
    float4 b0 = *(const float4*)(x + (size_t)t0 * 2048 + c + 4);
    float4 a1 = *(const float4*)(x + (size_t)(t0 + 1) * 2048 + c);
    float4 b1 = *(const float4*)(x + (size_t)(t0 + 1) * 2048 + c + 4);
    float xf0[8] = {a0.x, a0.y, a0.z, a0.w, b0.x, b0.y, b0.z, b0.w};
    float xf1[8] = {a1.x, a1.y, a1.z, a1.w, b1.x, b1.y, b1.z, b1.w};

    bf16x8 v0, v1;
#pragma unroll
    for (int j = 0; j < 8; ++j) { v0[j] = f2bf(xf0[j]); v1[j] = f2bf(xf1[j]); }
    *(bf16x8*)(Abuf + (size_t)t0 * 2176 + c) = v0;
    *(bf16x8*)(Abuf + (size_t)(t0 + 1) * 2176 + c) = v1;

    float acc0[8], acc1[8];
#pragma unroll
    for (int e = 0; e < 8; ++e) { acc0[e] = 0.0f; acc1[e] = 0.0f; }
#pragma unroll
    for (int e = 0; e < 8; ++e) {
      float4 g0 = *(const float4*)(gw + e * 2048 + c);
      float4 g1 = *(const float4*)(gw + e * 2048 + c + 4);
      float gg[8] = {g0.x, g0.y, g0.z, g0.w, g1.x, g1.y, g1.z, g1.w};
#pragma unroll
      for (int j = 0; j < 8; ++j) {
        acc0[e] += xf0[j] * gg[j];
        acc1[e] += xf1[j] * gg[j];
      }
    }
#pragma unroll
    for (int e = 0; e < 8; ++e) { red[tid][e] = acc0[e]; red[tid][8 + e] = acc1[e]; }
    __syncthreads();
    {
      const int p = tid & 15, ch = tid >> 4;
      float s = 0.0f;
#pragma unroll
      for (int i = 0; i < 16; ++i) s += red[ch * 16 + i][p];
      red2[ch][p] = s;
    }
    __syncthreads();
    if (tid < 2) {
      float lg[8];
#pragma unroll
      for (int e = 0; e < 8; ++e) {
        float s = 0.0f;
#pragma unroll
        for (int ch = 0; ch < 16; ++ch) s += red2[ch][tid * 8 + e];
        lg[e] = s;
      }
      int a = 0;
      for (int e = 1; e < 8; ++e) if (lg[e] > lg[a]) a = e;
      int bb = (a == 0) ? 1 : 0;
      for (int e = 0; e < 8; ++e) if (e != a && lg[e] > lg[bb]) bb = e;
      const float d = __expf(lg[bb] - lg[a]);
      float o[8] = {0, 0, 0, 0, 0, 0, 0, 0};
      o[a] = 1.0f / (1.0f + d);
      o[bb] = d / (1.0f + d);
      const int t = t0 + tid;
#pragma unroll
      for (int e = 0; e < 8; ++e) cw[t * 8 + e] = o[e];
    }
    __syncthreads();  // all Abuf-x + cw stores drained to L2
    if (tid == 0) flag_release(&tokflag[b - 2240]);
    return;
  }
  // ---- t2: Abuf[:,2048:] = bf16(16*cw * (x @ A2^T)) ----
  const int idx = b - 4288;
  const int tile = idx >> 3, e = idx & 7;
  const int t0 = tile * 16;
  // spin: 8 token flags (producers: router blocks tile*8 .. tile*8+7), 128 A2 rows
  if (tid < 8) flag_spin(&tokflag[tile * 8 + tid]);
  if (tid >= 64 && tid < 192) flag_spin(&a2flag[tid - 64]);
  __syncthreads();
  __threadfence();  // acquire: invalidate stale L1/L2 before data reads

  const int wave = tid >> 6, lane = tid & 63;
  const int m = lane & 15, q = lane >> 4;
  const __bf16* arow = Abuf + (size_t)(t0 + m) * 2176 + wave * 512 + q * 8;
  const __bf16* brow = A2 + (size_t)(e * 16 + m) * 2048 + wave * 512 + q * 8;
  f32x4 acc0 = {}, acc1 = {};
#pragma unroll
  for (int ks = 0; ks < 16; ks += 2) {
    bf16x8 af0 = *(const bf16x8*)(arow + ks * 32);
    bf16x8 bf0 = *(const bf16x8*)(brow + ks * 32);
    bf16x8 af1 = *(const bf16x8*)(arow + ks * 32 + 32);
    bf16x8 bf1 = *(const bf16x8*)(brow + ks * 32 + 32);
    acc0 = __builtin_amdgcn_mfma_f32_16x16x32_bf16(af0, bf0, acc0, 0, 0, 0);
    acc1 = __builtin_amdgcn_mfma_f32_16x16x32_bf16(af1, bf1, acc1, 0, 0, 0);
  }
  part[wave][lane] = acc0 + acc1;
  __syncthreads();
  if (wave == 0) {
    f32x4 s = part[0][lane] + part[1][lane] + part[2][lane] + part[3][lane];
    // C layout: col = lane&15 (n within expert), row = q*4+reg (token)
#pragma unroll
    for (int rg = 0; rg < 4; ++rg) {
      const int t = t0 + q * 4 + rg;
      Abuf[(size_t)t * 2176 + 2048 + e * 16 + m] =
          f2bf(s[rg] * 16.0f * cw[t * 8 + e]);
    }
  }
}

// ---------------- MFMA GEMM: C[m,n] = sum_k A[m,k]*B[n,k] (both K-major) ----
// 128x128 tile, BK=64, 512 threads (8 waves, wave-tile 64x32). Grid 32x16 =
// 512 blocks -> 2 blocks x 8 waves = 16 waves/CU; staging 256 B/MFMA.
// XOR k-chunk swizzle as R1.
__global__ __launch_bounds__(512, 4) void mfma_gemm_bt(
    const __bf16* __restrict__ A, const __bf16* __restrict__ B,
    float* __restrict__ C, int lda, int ldb, int ldc, int kiters) {
  __shared__ __align__(16) __bf16 As[128 * 64];
  __shared__ __align__(16) __bf16 Bs[128 * 64];
  const int tid = threadIdx.x;
  const int wave = tid >> 6;
  const int lane = tid & 63;
  const int tm = blockIdx.x * 128;
  const int tn = blockIdx.y * 128;

  const int wm = (wave >> 2) * 64;  // 2 m-tiles x 4 n-tiles of 64x32
  const int wn = (wave & 3) * 32;
  const int srow = lane >> 3;                 // row within 8-row staging chunk
  const int skoff = ((lane & 7) ^ srow) * 8;  // XOR-swizzled k offset (elems)

  const int rlo = lane & 7;
  const int rb3 = (lane >> 3) & 1;
  const int qb = lane >> 4;

  f32x4 acc[4][2] = {};

  int kcur = 0;
  for (int kt = 0; kt < kiters; ++kt) {
#pragma unroll
    for (int r = 0; r < 2; ++r) {
      const int ch = r * 8 + wave;  // 16 chunks of 8 rows each
      ld_lds16(A + (size_t)(tm + ch * 8 + srow) * lda + kcur + skoff, &As[ch * 512]);
      ld_lds16(B + (size_t)(tn + ch * 8 + srow) * ldb + kcur + skoff, &Bs[ch * 512]);
    }
    __syncthreads();
#pragma unroll
    for (int ks = 0; ks < 2; ++ks) {
      bf16x8 af[4], bfg[2];
      const int q8 = ((ks * 4 + qb) ^ rlo) * 8;
#pragma unroll
      for (int i = 0; i < 4; ++i) {
        const int rh = ((wm + i * 16) >> 3) + rb3;
        af[i] = *(const bf16x8*)&As[rh * 512 + rlo * 64 + q8];
      }
#pragma unroll
      for (int j = 0; j < 2; ++j) {
        const int rh = ((wn + j * 16) >> 3) + rb3;
        bfg[j] = *(const bf16x8*)&Bs[rh * 512 + rlo * 64 + q8];
      }
#pragma unroll
      for (int i = 0; i < 4; ++i)
#pragma unroll
        for (int j = 0; j < 2; ++j)
          acc[i][j] = __builtin_amdgcn_mfma_f32_16x16x32_bf16(af[i], bfg[j], acc[i][j], 0, 0, 0);
    }
    __syncthreads();
    kcur += 64;
  }

  // C/D layout: col = lane&15, row = (lane>>4)*4 + reg
  const int crow0 = tm + wm + (lane >> 4) * 4;
  const int ccol0 = tn + wn + (lane & 15);
#pragma unroll
  for (int i = 0; i < 4; ++i)
#pragma unroll
    for (int j = 0; j < 2; ++j)
#pragma unroll
      for (int rg = 0; rg < 4; ++rg)
        C[(size_t)(crow0 + i * 16 + rg) * ldc + ccol0 + j * 16] = acc[i][j][rg];
}

extern "C" void kernel_launch(void* const* d_in, const int* in_sizes, int n_in,
                              void* d_out, int out_size, void* d_ws, size_t ws_size,
                              hipStream_t stream) {
  const float* x = (const float*)d_in[0];       // [2,2048,2048] -> [4096,2048]
  const float* weight = (const float*)d_in[1];  // [2048,2048]
  const float* gate_w = (const float*)d_in[2];  // [8,2048]
  const float* A_w = (const float*)d_in[3];     // [8,16,2048] == [128,2048]
  const float* B_w = (const float*)d_in[4];     // [8,2048,16]
  float* out = (float*)d_out;                   // [4096,2048]

  char* ws = (char*)d_ws;
  __bf16* Abuf = (__bf16*)ws;                // [4096,2176] bf16 = 17,825,792 B
  __bf16* Bfull = (__bf16*)(ws + 17825792);  // [2048,2176] bf16 =  8,912,896 B
  __bf16* A2 = (__bf16*)(ws + 26738688);     // [128,2048]  bf16 =    524,288 B
  float* cw = (float*)(ws + 27262976);       // [4096,8]    f32  =    131,072 B
  int* tokflag = (int*)(ws + 27394048);      // [2048] int (poison 0xAA.. != MAGIC)
  int* a2flag = (int*)(ws + 27402240);       // [128] int

  // 1. mega-setup: conversions + router + t2, flag-ordered, one dispatch
  setup_kernel<<<6336, 256, 0, stream>>>(weight, A_w, B_w, x, gate_w, Bfull, A2,
                                         Abuf, cw, tokflag, a2flag);
  // 2. out = Abuf @ Bfull^T  (K=2176 fuses base + LoRA-up)
  mfma_gemm_bt<<<dim3(32, 16), 512, 0, stream>>>(Abuf, Bfull, out, 2176, 2176,
                                                 2048, 34);
}

// Round 7
// 174.558 us; speedup vs baseline: 3.4604x; 3.4604x over previous
//
#include <hip/hip_runtime.h>
#include <hip/hip_bf16.h>

// MoLoRA = base linear + top-2 routed LoRA.
//   Abuf[T,2176] = [ bf16(x) | bf16(alpha*cw*(x@A2^T)) ]      (A2 = A_w as [128,2048])
//   Bfull[O,2176] = [ bf16(W) | bf16(B2^T) ]   (B2[e*16+r,o]=B_w[e,o,r])
//   out[T,O] = Abuf @ Bfull^T     -- single bf16 MFMA GEMM, K=2176
// T=4096, H=2048, O=2048, E=8, R=16, Kaug=2176.
//
// R1: XOR k-chunk LDS swizzle -> SQ_LDS_BANK_CONFLICT 1.34e7 -> 0.
// R2-R4: tile/occupancy: 128x128 tile, 512 thr (8 waves of 64x32), 512 blocks
//   = 16 waves/CU -> 44.9 us (813 TF, the HIP-source m97-structure plateau).
// R5: flag-ordered single-dispatch fusion of setup+t2 REGRESSED 20x (2048
//   consumer blocks spinning on agent-scope atomics serialize L2; lesson:
//   kernel-boundary barrier beats fine-grained cross-block sync at this
//   fan-in). Reverted to the R5/three-dispatch structure: setup (prep+router),
//   t2_scale, main GEMM. Each dispatch is at its structural floor:
//   setup ~16us (~1.3x BW roofline), t2 ~8us, GEMM 44.9us (m97 plateau).

typedef __bf16 bf16x8 __attribute__((ext_vector_type(8)));
typedef float f32x4 __attribute__((ext_vector_type(4)));

__device__ __forceinline__ __bf16 f2bf(float f) {
  union { float f; unsigned u; } v; v.f = f;
  unsigned r = (v.u + 0x7FFFu + ((v.u >> 16) & 1u)) >> 16;  // RNE
  unsigned short s = (unsigned short)r;
  return __builtin_bit_cast(__bf16, s);
}

__device__ __forceinline__ void ld_lds16(const void* g, void* l) {
  __builtin_amdgcn_global_load_lds((__attribute__((address_space(1))) void*)g,
                                   (__attribute__((address_space(3))) void*)l,
                                   16, 0, 0);
}

// ---------------- setup: prep (W/A2/Bw-pack) + conv_router, one dispatch ----
// blocks 0..2175   : row conversion W->Bfull / Aw->A2
// blocks 2176..2239: Bw pack into Bfull[:,2048:]
// blocks 2240..4287: conv_router (2 tokens each): x->bf16->Abuf + fp32 logits
//                    + top-2 -> cw
__global__ __launch_bounds__(256) void setup_kernel(
    const float* __restrict__ W, const float* __restrict__ Aw,
    const float* __restrict__ Bw, const float* __restrict__ x,
    const float* __restrict__ gw, __bf16* __restrict__ Bfull,
    __bf16* __restrict__ A2, __bf16* __restrict__ Abuf,
    float* __restrict__ cw) {
  const int b = blockIdx.x, tid = threadIdx.x;
  if (b < 2176) {
    const float* src = (b < 2048) ? (W + (size_t)b * 2048)
                                  : (Aw + (size_t)(b - 2048) * 2048);
    __bf16* dst = (b < 2048) ? (Bfull + (size_t)b * 2176)
                             : (A2 + (size_t)(b - 2048) * 2048);
    const int c = tid * 8;
    float4 a = *(const float4*)(src + c);
    float4 d = *(const float4*)(src + c + 4);
    bf16x8 v;
    v[0] = f2bf(a.x); v[1] = f2bf(a.y); v[2] = f2bf(a.z); v[3] = f2bf(a.w);
    v[4] = f2bf(d.x); v[5] = f2bf(d.y); v[6] = f2bf(d.z); v[7] = f2bf(d.w);
    *(bf16x8*)(dst + c) = v;
    return;
  }
  if (b < 2240) {
    const int idx = (b - 2176) * 256 + tid;  // 0..16383
    const int e = idx >> 11, o = idx & 2047;
    const float4* s = (const float4*)(Bw + ((size_t)e * 2048 + o) * 16);
    float4 v0 = s[0], v1 = s[1], v2 = s[2], v3 = s[3];
    __bf16* d = Bfull + (size_t)o * 2176 + 2048 + e * 16;
    bf16x8 lo, hi;
    lo[0] = f2bf(v0.x); lo[1] = f2bf(v0.y); lo[2] = f2bf(v0.z); lo[3] = f2bf(v0.w);
    lo[4] = f2bf(v1.x); lo[5] = f2bf(v1.y); lo[6] = f2bf(v1.z); lo[7] = f2bf(v1.w);
    hi[0] = f2bf(v2.x); hi[1] = f2bf(v2.y); hi[2] = f2bf(v2.z); hi[3] = f2bf(v2.w);
    hi[4] = f2bf(v3.x); hi[5] = f2bf(v3.y); hi[6] = f2bf(v3.z); hi[7] = f2bf(v3.w);
    *(bf16x8*)d = lo;
    *(bf16x8*)(d + 8) = hi;
    return;
  }
  // ---- conv_router ----
  __shared__ float red[256][17];
  __shared__ float red2[16][17];
  const int t0 = (b - 2240) * 2;
  const int c = tid * 8;

  float4 a0 = *(const float4*)(x + (size_t)t0 * 2048 + c);
  float4 b0 = *(const float4*)(x + (size_t)t0 * 2048 + c + 4);
  float4 a1 = *(const float4*)(x + (size_t)(t0 + 1) * 2048 + c);
  float4 b1 = *(const float4*)(x + (size_t)(t0 + 1) * 2048 + c + 4);
  float xf0[8] = {a0.x, a0.y, a0.z, a0.w, b0.x, b0.y, b0.z, b0.w};
  float xf1[8] = {a1.x, a1.y, a1.z, a1.w, b1.x, b1.y, b1.z, b1.w};

  bf16x8 v0, v1;
#pragma unroll
  for (int j = 0; j < 8; ++j) { v0[j] = f2bf(xf0[j]); v1[j] = f2bf(xf1[j]); }
  *(bf16x8*)(Abuf + (size_t)t0 * 2176 + c) = v0;
  *(bf16x8*)(Abuf + (size_t)(t0 + 1) * 2176 + c) = v1;

  float acc0[8], acc1[8];
#pragma unroll
  for (int e = 0; e < 8; ++e) { acc0[e] = 0.0f; acc1[e] = 0.0f; }
#pragma unroll
  for (int e = 0; e < 8; ++e) {
    float4 g0 = *(const float4*)(gw + e * 2048 + c);
    float4 g1 = *(const float4*)(gw + e * 2048 + c + 4);
    float gg[8] = {g0.x, g0.y, g0.z, g0.w, g1.x, g1.y, g1.z, g1.w};
#pragma unroll
    for (int j = 0; j < 8; ++j) {
      acc0[e] += xf0[j] * gg[j];
      acc1[e] += xf1[j] * gg[j];
    }
  }
#pragma unroll
  for (int e = 0; e < 8; ++e) { red[tid][e] = acc0[e]; red[tid][8 + e] = acc1[e]; }
  __syncthreads();
  {
    const int p = tid & 15, ch = tid >> 4;
    float s = 0.0f;
#pragma unroll
    for (int i = 0; i < 16; ++i) s += red[ch * 16 + i][p];
    red2[ch][p] = s;
  }
  __syncthreads();
  if (tid < 2) {
    float lg[8];
#pragma unroll
    for (int e = 0; e < 8; ++e) {
      float s = 0.0f;
#pragma unroll
      for (int ch = 0; ch < 16; ++ch) s += red2[ch][tid * 8 + e];
      lg[e] = s;
    }
    int a = 0;
    for (int e = 1; e < 8; ++e) if (lg[e] > lg[a]) a = e;
    int bb = (a == 0) ? 1 : 0;
    for (int e = 0; e < 8; ++e) if (e != a && lg[e] > lg[bb]) bb = e;
    const float d = __expf(lg[bb] - lg[a]);
    float o[8] = {0, 0, 0, 0, 0, 0, 0, 0};
    o[a] = 1.0f / (1.0f + d);
    o[bb] = d / (1.0f + d);
    const int t = t0 + tid;
#pragma unroll
    for (int e = 0; e < 8; ++e) cw[t * 8 + e] = o[e];
  }
}

// ---------------- t2_scale: Abuf[:,2048:] = bf16(16*cw * (x @ A2^T)) ---------
// grid (256 token-tiles, 8 experts), 256 threads; wave w covers k-quarter
// [w*512, w*512+512), then LDS reduce + scale + store by wave 0.
__global__ __launch_bounds__(256) void t2_scale(
    const __bf16* __restrict__ Abuf_x, const __bf16* __restrict__ A2,
    const float* __restrict__ cw, __bf16* __restrict__ Abuf) {
  __shared__ f32x4 part[4][64];
  const int tid = threadIdx.x;
  const int wave = tid >> 6, lane = tid & 63;
  const int t0 = blockIdx.x * 16;
  const int e = blockIdx.y;
  const int m = lane & 15, q = lane >> 4;

  const __bf16* arow = Abuf_x + (size_t)(t0 + m) * 2176 + wave * 512 + q * 8;
  const __bf16* brow = A2 + (size_t)(e * 16 + m) * 2048 + wave * 512 + q * 8;
  f32x4 acc0 = {}, acc1 = {};
#pragma unroll
  for (int ks = 0; ks < 16; ks += 2) {
    bf16x8 af0 = *(const bf16x8*)(arow + ks * 32);
    bf16x8 bf0 = *(const bf16x8*)(brow + ks * 32);
    bf16x8 af1 = *(const bf16x8*)(arow + ks * 32 + 32);
    bf16x8 bf1 = *(const bf16x8*)(brow + ks * 32 + 32);
    acc0 = __builtin_amdgcn_mfma_f32_16x16x32_bf16(af0, bf0, acc0, 0, 0, 0);
    acc1 = __builtin_amdgcn_mfma_f32_16x16x32_bf16(af1, bf1, acc1, 0, 0, 0);
  }
  part[wave][lane] = acc0 + acc1;
  __syncthreads();
  if (wave == 0) {
    f32x4 s = part[0][lane] + part[1][lane] + part[2][lane] + part[3][lane];
    // C layout: col = lane&15 (n within expert), row = q*4+reg (token)
#pragma unroll
    for (int rg = 0; rg < 4; ++rg) {
      const int t = t0 + q * 4 + rg;
      Abuf[(size_t)t * 2176 + 2048 + e * 16 + m] =
          f2bf(s[rg] * 16.0f * cw[t * 8 + e]);
    }
  }
}

// ---------------- MFMA GEMM: C[m,n] = sum_k A[m,k]*B[n,k] (both K-major) ----
// 128x128 tile, BK=64, 512 threads (8 waves, wave-tile 64x32). Grid 32x16 =
// 512 blocks -> 2 blocks x 8 waves = 16 waves/CU; staging 256 B/MFMA.
// XOR k-chunk swizzle as R1.
__global__ __launch_bounds__(512, 4) void mfma_gemm_bt(
    const __bf16* __restrict__ A, const __bf16* __restrict__ B,
    float* __restrict__ C, int lda, int ldb, int ldc, int kiters) {
  __shared__ __align__(16) __bf16 As[128 * 64];
  __shared__ __align__(16) __bf16 Bs[128 * 64];
  const int tid = threadIdx.x;
  const int wave = tid >> 6;
  const int lane = tid & 63;
  const int tm = blockIdx.x * 128;
  const int tn = blockIdx.y * 128;

  const int wm = (wave >> 2) * 64;  // 2 m-tiles x 4 n-tiles of 64x32
  const int wn = (wave & 3) * 32;
  const int srow = lane >> 3;                 // row within 8-row staging chunk
  const int skoff = ((lane & 7) ^ srow) * 8;  // XOR-swizzled k offset (elems)

  const int rlo = lane & 7;
  const int rb3 = (lane >> 3) & 1;
  const int qb = lane >> 4;

  f32x4 acc[4][2] = {};

  int kcur = 0;
  for (int kt = 0; kt < kiters; ++kt) {
#pragma unroll
    for (int r = 0; r < 2; ++r) {
      const int ch = r * 8 + wave;  // 16 chunks of 8 rows each
      ld_lds16(A + (size_t)(tm + ch * 8 + srow) * lda + kcur + skoff, &As[ch * 512]);
      ld_lds16(B + (size_t)(tn + ch * 8 + srow) * ldb + kcur + skoff, &Bs[ch * 512]);
    }
    __syncthreads();
#pragma unroll
    for (int ks = 0; ks < 2; ++ks) {
      bf16x8 af[4], bfg[2];
      const int q8 = ((ks * 4 + qb) ^ rlo) * 8;
#pragma unroll
      for (int i = 0; i < 4; ++i) {
        const int rh = ((wm + i * 16) >> 3) + rb3;
        af[i] = *(const bf16x8*)&As[rh * 512 + rlo * 64 + q8];
      }
#pragma unroll
      for (int j = 0; j < 2; ++j) {
        const int rh = ((wn + j * 16) >> 3) + rb3;
        bfg[j] = *(const bf16x8*)&Bs[rh * 512 + rlo * 64 + q8];
      }
#pragma unroll
      for (int i = 0; i < 4; ++i)
#pragma unroll
        for (int j = 0; j < 2; ++j)
          acc[i][j] = __builtin_amdgcn_mfma_f32_16x16x32_bf16(af[i], bfg[j], acc[i][j], 0, 0, 0);
    }
    __syncthreads();
    kcur += 64;
  }

  // C/D layout: col = lane&15, row = (lane>>4)*4 + reg
  const int crow0 = tm + wm + (lane >> 4) * 4;
  const int ccol0 = tn + wn + (lane & 15);
#pragma unroll
  for (int i = 0; i < 4; ++i)
#pragma unroll
    for (int j = 0; j < 2; ++j)
#pragma unroll
      for (int rg = 0; rg < 4; ++rg)
        C[(size_t)(crow0 + i * 16 + rg) * ldc + ccol0 + j * 16] = acc[i][j][rg];
}

extern "C" void kernel_launch(void* const* d_in, const int* in_sizes, int n_in,
                              void* d_out, int out_size, void* d_ws, size_t ws_size,
                              hipStream_t stream) {
  const float* x = (const float*)d_in[0];       // [2,2048,2048] -> [4096,2048]
  const float* weight = (const float*)d_in[1];  // [2048,2048]
  const float* gate_w = (const float*)d_in[2];  // [8,2048]
  const float* A_w = (const float*)d_in[3];     // [8,16,2048] == [128,2048]
  const float* B_w = (const float*)d_in[4];     // [8,2048,16]
  float* out = (float*)d_out;                   // [4096,2048]

  char* ws = (char*)d_ws;
  __bf16* Abuf = (__bf16*)ws;                // [4096,2176] bf16 = 17,825,792 B
  __bf16* Bfull = (__bf16*)(ws + 17825792);  // [2048,2176] bf16 =  8,912,896 B
  __bf16* A2 = (__bf16*)(ws + 26738688);     // [128,2048]  bf16 =    524,288 B
  float* cw = (float*)(ws + 27262976);       // [4096,8]    f32  =    131,072 B

  // 1. setup: W/Aw/Bw prep + x->bf16 + fp32 router (one dispatch)
  setup_kernel<<<4288, 256, 0, stream>>>(weight, A_w, B_w, x, gate_w, Bfull, A2,
                                         Abuf, cw);
  // 2. LoRA-down + scale into Abuf[:,2048:2176]
  t2_scale<<<dim3(256, 8), 256, 0, stream>>>(Abuf, A2, cw, Abuf);
  // 3. out = Abuf @ Bfull^T  (K=2176 fuses base + LoRA-up)
  mfma_gemm_bt<<<dim3(32, 16), 512, 0, stream>>>(Abuf, Bfull, out, 2176, 2176,
                                                 2048, 34);
}